// Round 5
// baseline (6350.884 us; speedup 1.0000x reference)
//
#include <hip/hip_runtime.h>
#include <hip/hip_fp16.h>
#include <math.h>

#define B_  64
#define T_  800
#define U_  64
#define V_  60
#define C_  512
#define K_  10
#define KX  576   // padded hx: [0..3]=x(3)+pad, [4..63]=w(60), [64..575]=h(512)
#define NWG 256
#define NTH 512
#define KQ  8     // k-split across the 8 waves of a WG
#define KSL 72    // KX / KQ
#define NB  4     // batches per group
#define GRPWG 16  // WGs per group (16 groups x 16 WGs)

typedef unsigned long long ull;

// ws layout (ull units):
//   [0 .. 65536)      hpair[2][B_][C_]      (h value lo32, tag hi32)
//   [65536 .. 131072) wpair[2][16][16][128] (win-partial lo32, tag hi32; 120 used)
#define WP_OFF 65536
#define WP_STRIDE 128

__device__ __forceinline__ float sigm(float v)  { return 1.f/(1.f+__expf(-v)); }
__device__ __forceinline__ float tanhx(float v) { return 1.f - 2.f/(__expf(2.f*v)+1.f); }

__launch_bounds__(NTH, 2)
__global__ void lstm_attn_persistent(
    const float* __restrict__ x,         // [B,T,3]
    const float* __restrict__ onehots,   // [B,U,V]
    const float* __restrict__ text_lens, // [B,1]
    const float* __restrict__ w_old,     // [B,V]
    const float* __restrict__ kappa_old, // [B,K]
    const float* __restrict__ prev_h,    // [B,C]
    const float* __restrict__ prev_c,    // [B,C]
    const float* __restrict__ W_ih,      // [4C, 63]
    const float* __restrict__ W_hh,      // [4C, C]
    const float* __restrict__ b_ih,      // [4C]
    const float* __restrict__ b_hh,      // [4C]
    const float* __restrict__ win_W,     // [30, C]
    const float* __restrict__ win_b,     // [30]
    ull* __restrict__ wsb,
    float* __restrict__ out)
{
  // out layout (flat, return order)
  const long OUT_WS  = 0;
  const long OUT_HS  = (long)B_*T_*V_;
  const long OUT_H   = OUT_HS + (long)B_*T_*C_;
  const long OUT_C   = OUT_H  + (long)B_*C_;
  const long OUT_W   = OUT_C  + (long)B_*C_;
  const long OUT_KAP = OUT_W  + (long)B_*V_;
  const long OUT_PHI = OUT_KAP+ (long)B_*K_;

  const int tid  = threadIdx.x;
  const int kq   = tid >> 6;        // wave id 0..7 = k-slice
  const int lane = tid & 63;
  const int bid  = blockIdx.x;
  const int grp  = bid & 15;        // group id (4 batches)
  const int gblk = bid >> 4;        // 0..15: 128-gate-col block
  const int b0   = grp * NB;

  __shared__ __align__(16) float hx[NB][KX];          // per-b extended input vector
  __shared__ __align__(16) float part[KQ][NB][2][68]; // gate k-slice partials (padded)
  __shared__ __align__(16) float hown[NB][32];        // this WG's own h channels
  __shared__ float wp_lds[GRPWG][120];                // gathered window partials
  __shared__ float p_lds[NB][32];
  __shared__ float kap_lds[NB][12];
  __shared__ float scale_lds[NB];
  __shared__ int   ids_lds[NB][64];

  // ---- persistent registers ----
  // permuted gate col gp = ch*4 + gate; WG owns gp in [gblk*128, gblk*128+128)
  // lane covers s=0: gp0 = gblk*128+lane, s=1: gp1 = gp0+64
  __half2 Wh2[KSL];                 // packed (col0, col1) f16 weights per k
  float bias2[2];
  {
    #pragma unroll
    for (int i = 0; i < KSL; ++i) {
      float wv[2];
      #pragma unroll
      for (int s = 0; s < 2; ++s) {
        int gp   = gblk*128 + lane + 64*s;
        int gate = gp & 3;
        int ch   = gp >> 2;
        int row  = gate*C_ + ch;
        int k = kq*KSL + i;
        float v;
        if      (k < 3)  v = W_ih[row*63 + k];
        else if (k == 3) v = 0.f;
        else if (k < 64) v = W_ih[row*63 + (k-1)];
        else             v = W_hh[row*C_ + (k-64)];
        wv[s] = v;
      }
      Wh2[i] = __floats2half2_rn(wv[0], wv[1]);
    }
    #pragma unroll
    for (int s = 0; s < 2; ++s) {
      int gp   = gblk*128 + lane + 64*s;
      int gate = gp & 3;
      int ch   = gp >> 2;
      int row  = gate*C_ + ch;
      bias2[s] = b_ih[row] + b_hh[row];
    }
  }

  // window weights for own 32 channels: tid<120 -> (bb=tid/30, j=tid%30)
  __half2 winw2[16];
  if (tid < 120) {
    int j = tid % 30;
    #pragma unroll
    for (int c2 = 0; c2 < 16; ++c2)
      winw2[c2] = __floats2half2_rn(win_W[j*C_ + gblk*32 + 2*c2],
                                    win_W[j*C_ + gblk*32 + 2*c2 + 1]);
  }
  float winb_r = (tid < 120) ? win_b[tid % 30] : 0.f;

  // LSTM cell state: tid<128 owns (bb = tid>>5, ch = gblk*32 + (tid&31))
  const int ub    = tid >> 5;       // 0..3 when tid<128
  const int chloc = tid & 31;
  const int mych  = gblk*32 + chloc;
  float c_reg = 0.f;
  if (tid < 128) c_reg = prev_c[(long)(b0 + ub)*C_ + mych];

  // ---- preamble staging ----
  for (int i = tid; i < NB*KX; i += NTH) {
    int bb = i / KX, k = i % KX;
    int b = b0 + bb;
    float v;
    if      (k < 3)  v = x[((long)b*T_ + 0)*3 + k];
    else if (k < 4)  v = 0.f;
    else if (k < 64) v = w_old[b*V_ + (k-4)];
    else             v = prev_h[(long)b*C_ + (k-64)];
    hx[bb][k] = v;
  }
  for (int i = tid; i < NB*K_; i += NTH)
    kap_lds[i/K_][i%K_] = kappa_old[(b0 + i/K_)*K_ + i%K_];
  if (tid < NB) scale_lds[tid] = (float)U_ / text_lens[b0 + tid];
  for (int i = tid; i < NB*U_; i += NTH) {          // one-hot -> char id
    int bb = i / U_, u = i % U_;
    const float* oh = onehots + ((long)(b0+bb)*U_ + u)*V_;
    int best = 0; float bv = oh[0];
    for (int vv = 1; vv < V_; ++vv) { float q = oh[vv]; if (q > bv) { bv = q; best = vv; } }
    ids_lds[bb][u] = best;
  }
  __syncthreads();

  ull* hpair = wsb;                 // [2][B][C] tagged h
  ull* wpair = wsb + WP_OFF;        // [2][16][16][128] tagged win-partials

  for (int t = 0; t < T_; ++t) {
    // ---- A: gates GEMM (k-split over waves; 2 cols/lane; f16 weights, fma_mix) ----
    float acc[NB][2];
    #pragma unroll
    for (int bb = 0; bb < NB; ++bb) {
      acc[bb][0] = (kq == 0) ? bias2[0] : 0.f;
      acc[bb][1] = (kq == 0) ? bias2[1] : 0.f;
    }
    #pragma unroll
    for (int bb = 0; bb < NB; ++bb) {
      const float* hxb = &hx[bb][kq*KSL];
      float a0 = acc[bb][0], a1 = acc[bb][1];
      #pragma unroll
      for (int i4 = 0; i4 < KSL/4; ++i4) {
        float4 h4 = *(const float4*)(hxb + i4*4);
        float2 w0 = __half22float2(Wh2[i4*4+0]);
        float2 w1 = __half22float2(Wh2[i4*4+1]);
        float2 w2 = __half22float2(Wh2[i4*4+2]);
        float2 w3 = __half22float2(Wh2[i4*4+3]);
        a0 = fmaf(w0.x, h4.x, a0);  a1 = fmaf(w0.y, h4.x, a1);
        a0 = fmaf(w1.x, h4.y, a0);  a1 = fmaf(w1.y, h4.y, a1);
        a0 = fmaf(w2.x, h4.z, a0);  a1 = fmaf(w2.y, h4.z, a1);
        a0 = fmaf(w3.x, h4.w, a0);  a1 = fmaf(w3.y, h4.w, a1);
      }
      acc[bb][0] = a0; acc[bb][1] = a1;
    }
    #pragma unroll
    for (int bb = 0; bb < NB; ++bb) {
      part[kq][bb][0][lane] = acc[bb][0];
      part[kq][bb][1][lane] = acc[bb][1];
    }
    __syncthreads();   // B

    // ---- C: cell update + h publish (tid<128) | zero w-slots | stage x(t+1) ----
    if (tid < 128) {
      const int sr = chloc >> 4, c4 = (chloc & 15) * 4;
      float4 s = make_float4(0.f, 0.f, 0.f, 0.f);
      #pragma unroll
      for (int q = 0; q < KQ; ++q) {
        float4 v = *(const float4*)&part[q][ub][sr][c4];
        s.x += v.x; s.y += v.y; s.z += v.z; s.w += v.w;
      }
      float ig = sigm(s.x), fg = sigm(s.y), gg = tanhx(s.z), og = sigm(s.w);
      float c = fg*c_reg + ig*gg;
      c_reg = c;
      float h = og * tanhx(c);
      int b = b0 + ub;
      hown[ub][chloc] = h;
      ull pk = ((ull)(unsigned)(t+1) << 32) | (ull)__float_as_uint(h);
      __hip_atomic_store(&hpair[(long)(t&1)*B_*C_ + (long)b*C_ + mych], pk,
                         __ATOMIC_RELAXED, __HIP_MEMORY_SCOPE_AGENT);
      out[OUT_HS + ((long)b*T_ + t)*C_ + mych] = h;
      if (t == T_-1) {
        out[OUT_H + (long)b*C_ + mych] = h;
        out[OUT_C + (long)b*C_ + mych] = c;
      }
    } else if (tid < 368) {
      int s0 = tid - 128;                 // zero 240 w-slots
      hx[s0/60][4 + s0%60] = 0.f;
    } else if (tid < 384) {
      int i = tid - 368, bb = i >> 2, k = i & 3;
      int tn = t + 1;
      hx[bb][k] = (k < 3 && tn < T_) ? x[((long)(b0+bb)*T_ + tn)*3 + k] : 0.f;
    }
    __syncthreads();   // C'

    // ---- C2 (waves 0-1): window partials from OWN h; publish ----
    if (tid < 120) {
      int bb = tid / 30;
      float s = 0.f;
      const float4* h4p = (const float4*)&hown[bb][0];
      #pragma unroll
      for (int q = 0; q < 8; ++q) {
        float4 hv = h4p[q];
        float2 wa = __half22float2(winw2[2*q]);
        float2 wb = __half22float2(winw2[2*q+1]);
        s = fmaf(wa.x, hv.x, s); s = fmaf(wa.y, hv.y, s);
        s = fmaf(wb.x, hv.z, s); s = fmaf(wb.y, hv.w, s);
      }
      ull pk = ((ull)(unsigned)(t+1) << 32) | (ull)__float_as_uint(s);
      __hip_atomic_store(&wpair[(((long)(t&1)*16 + grp)*GRPWG + gblk)*WP_STRIDE + tid],
                         pk, __ATOMIC_RELAXED, __HIP_MEMORY_SCOPE_AGENT);
    }

    // ---- G1 (tid<240): gather 16x120 window partials  ||  G2 (waves 4-7): gather h ----
    if (tid < 240) {
      const ull* src = wpair + ((long)(t&1)*16 + grp)*GRPWG*WP_STRIDE;
      const int want = t + 1;
      int wg_[8], i_[8];
      long a_[8];
      #pragma unroll
      for (int q = 0; q < 8; ++q) {
        int c = tid*8 + q;
        wg_[q] = c / 120; i_[q] = c % 120;
        a_[q] = (long)wg_[q]*WP_STRIDE + i_[q];
      }
      ull v[8];
      while (true) {
        bool ok = true;
        #pragma unroll
        for (int q = 0; q < 8; ++q) {
          v[q] = __hip_atomic_load(&src[a_[q]], __ATOMIC_RELAXED, __HIP_MEMORY_SCOPE_AGENT);
          ok &= ((int)(v[q] >> 32) >= want);
        }
        if (ok) break;
      }
      #pragma unroll
      for (int q = 0; q < 8; ++q)
        wp_lds[wg_[q]][i_[q]] = __uint_as_float((unsigned)v[q]);
    } else if (tid >= 256) {
      const int tid2 = tid - 256;   // 0..255
      const ull* hsrc = hpair + (long)(t&1)*B_*C_ + (long)b0*C_ + (long)tid2*8;
      const int want = t + 1;
      ull v[8];
      while (true) {
        bool ok = true;
        #pragma unroll
        for (int q = 0; q < 8; ++q) {
          v[q] = __hip_atomic_load(&hsrc[q], __ATOMIC_RELAXED, __HIP_MEMORY_SCOPE_AGENT);
          ok &= ((int)(v[q] >> 32) >= want);
        }
        if (ok) break;
      }
      int off = tid2 * 8;
      int bb = off >> 9, k = off & 511;
      *(float4*)&hx[bb][64 + k] = make_float4(
          __uint_as_float((unsigned)v[0]), __uint_as_float((unsigned)v[1]),
          __uint_as_float((unsigned)v[2]), __uint_as_float((unsigned)v[3]));
      *(float4*)&hx[bb][64 + k + 4] = make_float4(
          __uint_as_float((unsigned)v[4]), __uint_as_float((unsigned)v[5]),
          __uint_as_float((unsigned)v[6]), __uint_as_float((unsigned)v[7]));
    }
    __syncthreads();   // J

    // ---- K: reduce 16 partials -> p = exp(.+winb); update kappa ----
    if (tid < 120) {
      int bb = tid / 30, j = tid % 30;
      float s = 0.f;
      #pragma unroll
      for (int wg = 0; wg < GRPWG; ++wg) s += wp_lds[wg][tid];
      float p = __expf(s + winb_r);
      p_lds[bb][j] = p;
      if (j >= 20) {
        float nk = kap_lds[bb][j-20] + p;
        kap_lds[bb][j-20] = nk;
        if (t == T_-1 && gblk == 0) out[OUT_KAP + (b0+bb)*K_ + (j-20)] = nk;
      }
    }
    __syncthreads();   // L

    // ---- M (waves 0-3): fused phi + w-scatter (wave = batch; u = lane) ----
    if (kq < NB) {
      int bb = kq, u = lane;
      float s = 0.f;
      float uf = (float)u;
      #pragma unroll
      for (int k = 0; k < K_; ++k) {
        float d = kap_lds[bb][k] - uf;
        s += p_lds[bb][k] * __expf(-p_lds[bb][10+k]*d*d);
      }
      float phiv = s * scale_lds[bb];
      atomicAdd(&hx[bb][4 + ids_lds[bb][u]], phiv);   // ds_add_f32, in-wave order
      if (t == T_-1 && gblk == 0) out[OUT_PHI + (b0+bb)*65 + u] = phiv;
    }
    if (t == T_-1 && gblk == 0 && tid < NB) {         // u = 64 tail of phi output
      int b2 = tid;
      float s2 = 0.f;
      #pragma unroll
      for (int k = 0; k < K_; ++k) {
        float d = kap_lds[b2][k] - 64.f;
        s2 += p_lds[b2][k] * __expf(-p_lds[b2][10+k]*d*d);
      }
      out[OUT_PHI + (b0+b2)*65 + 64] = s2 * scale_lds[b2];
    }
    __syncthreads();   // N: scatter complete -> w readable

    // ---- O: rotated ws-store (one WG of the group per step) ----
    if (gblk == (t & 15) && tid < 240) {
      int bb = tid / 60, v = tid % 60;
      float wv = hx[bb][4+v];
      out[OUT_WS + ((long)(b0+bb)*T_ + t)*V_ + v] = wv;
      if (t == T_-1) out[OUT_W + (b0+bb)*V_ + v] = wv;
    }
    // no sync: O and next-A only read hx; first hx write is next-C (post-B sync)
  }
}

extern "C" void kernel_launch(void* const* d_in, const int* in_sizes, int n_in,
                              void* d_out, int out_size, void* d_ws, size_t ws_size,
                              hipStream_t stream) {
  const float* x         = (const float*)d_in[0];
  const float* onehots   = (const float*)d_in[1];
  const float* text_lens = (const float*)d_in[2];
  const float* w_old     = (const float*)d_in[3];
  const float* kappa_old = (const float*)d_in[4];
  const float* prev_h    = (const float*)d_in[5];
  const float* prev_c    = (const float*)d_in[6];
  const float* W_ih      = (const float*)d_in[7];
  const float* W_hh      = (const float*)d_in[8];
  const float* b_ih      = (const float*)d_in[9];
  const float* b_hh      = (const float*)d_in[10];
  const float* win_W     = (const float*)d_in[11];
  const float* win_b     = (const float*)d_in[12];
  ull*   wsb = (ull*)d_ws;
  float* out = (float*)d_out;

  // zero tagged regions (stale tags from prior replay must read < 1)
  hipMemsetAsync(d_ws, 0, 1048576, stream);

  lstm_attn_persistent<<<NWG, NTH, 0, stream>>>(
      x, onehots, text_lens, w_old, kappa_old, prev_h, prev_c,
      W_ih, W_hh, b_ih, b_hh, win_W, win_b, wsb, out);
}

// Round 6
// 4436.912 us; speedup vs baseline: 1.4314x; 1.4314x over previous
//
#include <hip/hip_runtime.h>
#include <math.h>

#define B_  64
#define T_  800
#define U_  64
#define V_  60
#define C_  512
#define K_  10
#define KX  576   // padded hx: [0..3]=x(3)+pad, [4..63]=w(60), [64..575]=h(512)
#define NWG 256
#define NTH 512
#define KQ  8     // k-split across the 8 waves of a WG
#define KSL 72    // KX / KQ
#define NB  4     // batches per group
#define GRPWG 16  // WGs per group (16 groups x 16 WGs)

// ws layout: ull hpair[2][B_][C_]  (value lo32, tag hi32) = 512KB, memset each launch
__device__ __forceinline__ float sigm(float v)  { return 1.f/(1.f+__expf(-v)); }
__device__ __forceinline__ float tanhx(float v) { return 1.f - 2.f/(__expf(2.f*v)+1.f); }

__global__ __launch_bounds__(NTH) __attribute__((amdgpu_waves_per_eu(2, 2)))
void lstm_attn_persistent(
    const float* __restrict__ x,         // [B,T,3]
    const float* __restrict__ onehots,   // [B,U,V]
    const float* __restrict__ text_lens, // [B,1]
    const float* __restrict__ w_old,     // [B,V]
    const float* __restrict__ kappa_old, // [B,K]
    const float* __restrict__ prev_h,    // [B,C]
    const float* __restrict__ prev_c,    // [B,C]
    const float* __restrict__ W_ih,      // [4C, 63]
    const float* __restrict__ W_hh,      // [4C, C]
    const float* __restrict__ b_ih,      // [4C]
    const float* __restrict__ b_hh,      // [4C]
    const float* __restrict__ win_W,     // [30, C]
    const float* __restrict__ win_b,     // [30]
    unsigned long long* __restrict__ hpair,
    float* __restrict__ out)
{
  // out layout (flat, return order)
  const long OUT_WS  = 0;
  const long OUT_HS  = (long)B_*T_*V_;
  const long OUT_H   = OUT_HS + (long)B_*T_*C_;
  const long OUT_C   = OUT_H  + (long)B_*C_;
  const long OUT_W   = OUT_C  + (long)B_*C_;
  const long OUT_KAP = OUT_W  + (long)B_*V_;
  const long OUT_PHI = OUT_KAP+ (long)B_*K_;

  const int tid  = threadIdx.x;
  const int kq   = tid >> 6;        // wave id 0..7 = k-slice
  const int lane = tid & 63;
  const int bid  = blockIdx.x;
  const int grp  = bid & 15;        // group id (4 batches)
  const int gblk = bid >> 4;        // 0..15: 128-gate-col block
  const int b0   = grp * NB;

  __shared__ __align__(16) float hx[NB][KX];          // per-b extended input vector
  __shared__ __align__(16) float part[KQ][NB][2][68]; // k-slice partials (s=col half), padded
  __shared__ float p_lds[NB][32];
  __shared__ float kap_lds[NB][12];
  __shared__ float scale_lds[NB];
  __shared__ int   ids_lds[NB][64];

  // ---- persistent registers ----
  // permuted gate col gp = ch*4 + gate; WG owns gp in [gblk*128, gblk*128+128)
  // lane covers s=0: gp0 = gblk*128+lane, s=1: gp1 = gp0+64
  float Wreg[2][KSL];
  float bias2[2];
  #pragma unroll
  for (int s = 0; s < 2; ++s) {
    int gp   = gblk*128 + lane + 64*s;
    int gate = gp & 3;
    int ch   = gp >> 2;
    int row  = gate*C_ + ch;
    #pragma unroll
    for (int i = 0; i < KSL; ++i) {
      int k = kq*KSL + i;
      float v;
      if      (k < 3)  v = W_ih[row*63 + k];
      else if (k == 3) v = 0.f;
      else if (k < 64) v = W_ih[row*63 + (k-1)];
      else             v = W_hh[row*C_ + (k-64)];
      Wreg[s][i] = v;
    }
    bias2[s] = b_ih[row] + b_hh[row];
  }

  // window rows: lanes 0..59 hold (j=lane%30, half=lane/30), 32-wide k-slice
  const int wj   = lane % 30;
  const int wh   = (lane < 60) ? (lane / 30) : 0;
  float winreg[32];
  #pragma unroll
  for (int i = 0; i < 32; ++i)
    winreg[i] = win_W[wj*C_ + kq*64 + wh*32 + i];

  // LSTM cell state: tid<128 owns (bb = tid>>5, ch = gblk*32 + (tid&31))
  const int ub    = tid >> 5;       // 0..3 when tid<128
  const int chloc = tid & 31;
  const int mych  = gblk*32 + chloc;
  float c_reg = 0.f;
  if (tid < 128) c_reg = prev_c[(long)(b0 + ub)*C_ + mych];

  float winb_r = (tid < 120) ? win_b[tid % 30] : 0.f;

  // ---- preamble staging ----
  for (int i = tid; i < NB*KX; i += NTH) {
    int bb = i / KX, k = i % KX;
    int b = b0 + bb;
    float v;
    if      (k < 3)  v = x[((long)b*T_ + 0)*3 + k];
    else if (k < 4)  v = 0.f;
    else if (k < 64) v = w_old[b*V_ + (k-4)];
    else             v = prev_h[(long)b*C_ + (k-64)];
    hx[bb][k] = v;
  }
  for (int i = tid; i < NB*K_; i += NTH)
    kap_lds[i/K_][i%K_] = kappa_old[(b0 + i/K_)*K_ + i%K_];
  if (tid < NB) scale_lds[tid] = (float)U_ / text_lens[b0 + tid];
  for (int i = tid; i < NB*U_; i += NTH) {          // one-hot -> char id
    int bb = i / U_, u = i % U_;
    const float* oh = onehots + ((long)(b0+bb)*U_ + u)*V_;
    int best = 0; float bv = oh[0];
    for (int vv = 1; vv < V_; ++vv) { float q = oh[vv]; if (q > bv) { bv = q; best = vv; } }
    ids_lds[bb][u] = best;
  }
  __syncthreads();

  for (int t = 0; t < T_; ++t) {
    // ---- A: gates GEMM (k-split over waves; 2 cols/lane; hx broadcast) ----
    float acc[NB][2];
    #pragma unroll
    for (int bb = 0; bb < NB; ++bb) {
      acc[bb][0] = (kq == 0) ? bias2[0] : 0.f;
      acc[bb][1] = (kq == 0) ? bias2[1] : 0.f;
    }
    #pragma unroll
    for (int bb = 0; bb < NB; ++bb) {
      const float* hxb = &hx[bb][kq*KSL];
      float a0 = acc[bb][0], a1 = acc[bb][1];
      #pragma unroll
      for (int i4 = 0; i4 < KSL/4; ++i4) {
        float4 h4 = *(const float4*)(hxb + i4*4);
        a0 = fmaf(Wreg[0][i4*4+0], h4.x, a0);
        a0 = fmaf(Wreg[0][i4*4+1], h4.y, a0);
        a0 = fmaf(Wreg[0][i4*4+2], h4.z, a0);
        a0 = fmaf(Wreg[0][i4*4+3], h4.w, a0);
        a1 = fmaf(Wreg[1][i4*4+0], h4.x, a1);
        a1 = fmaf(Wreg[1][i4*4+1], h4.y, a1);
        a1 = fmaf(Wreg[1][i4*4+2], h4.z, a1);
        a1 = fmaf(Wreg[1][i4*4+3], h4.w, a1);
      }
      acc[bb][0] = a0; acc[bb][1] = a1;
    }
    #pragma unroll
    for (int bb = 0; bb < NB; ++bb) {
      part[kq][bb][0][lane] = acc[bb][0];
      part[kq][bb][1][lane] = acc[bb][1];
    }
    __syncthreads();   // B

    // ---- C: cell update + fused (h,tag) publish | zero w-slots | stage x(t+1) ----
    if (tid < 128) {
      // cols for channel mych: gp=4*mych+gate -> s = chloc>>4, lane4 = (chloc&15)*4
      const int sr = chloc >> 4, c4 = (chloc & 15) * 4;
      float4 s = make_float4(0.f, 0.f, 0.f, 0.f);
      #pragma unroll
      for (int q = 0; q < KQ; ++q) {
        float4 v = *(const float4*)&part[q][ub][sr][c4];
        s.x += v.x; s.y += v.y; s.z += v.z; s.w += v.w;
      }
      float ig = sigm(s.x), fg = sigm(s.y), gg = tanhx(s.z), og = sigm(s.w);
      float c = fg*c_reg + ig*gg;
      c_reg = c;
      float h = og * tanhx(c);
      int b = b0 + ub;
      unsigned long long pk =
          ((unsigned long long)(unsigned)(t+1) << 32) | (unsigned long long)__float_as_uint(h);
      __hip_atomic_store(&hpair[(long)(t&1)*B_*C_ + (long)b*C_ + mych], pk,
                         __ATOMIC_RELAXED, __HIP_MEMORY_SCOPE_AGENT);
      out[OUT_HS + ((long)b*T_ + t)*C_ + mych] = h;
      if (t == T_-1) {
        out[OUT_H + (long)b*C_ + mych] = h;
        out[OUT_C + (long)b*C_ + mych] = c;
      }
    } else if (tid < 368) {
      int s0 = tid - 128;                 // zero 240 w-slots
      hx[s0/60][4 + s0%60] = 0.f;
    } else if (tid < 384) {
      int i = tid - 368, bb = i >> 2, k = i & 3;
      int tn = t + 1;
      hx[bb][k] = (k < 3 && tn < T_) ? x[((long)(b0+bb)*T_ + tn)*3 + k] : 0.f;
    }
    // no sync: G touches disjoint LDS (hx h-region), gated by data-dependency poll

    // ---- G: poll-gather fused (h,tag) pairs -> hx h-region ----
    {
      const unsigned long long* src = hpair + (long)(t&1)*B_*C_;
      const long base = (long)b0*C_ + tid*4;
      const int want = t + 1;
      unsigned long long v0, v1, v2, v3;
      while (true) {
        v0 = __hip_atomic_load(&src[base+0], __ATOMIC_RELAXED, __HIP_MEMORY_SCOPE_AGENT);
        v1 = __hip_atomic_load(&src[base+1], __ATOMIC_RELAXED, __HIP_MEMORY_SCOPE_AGENT);
        v2 = __hip_atomic_load(&src[base+2], __ATOMIC_RELAXED, __HIP_MEMORY_SCOPE_AGENT);
        v3 = __hip_atomic_load(&src[base+3], __ATOMIC_RELAXED, __HIP_MEMORY_SCOPE_AGENT);
        if ((int)(v0 >> 32) >= want && (int)(v1 >> 32) >= want &&
            (int)(v2 >> 32) >= want && (int)(v3 >> 32) >= want) break;
      }
      int off = tid * 4;
      int bb = off >> 9, k = off & 511;
      *(float4*)&hx[bb][64 + k] = make_float4(
          __uint_as_float((unsigned)v0), __uint_as_float((unsigned)v1),
          __uint_as_float((unsigned)v2), __uint_as_float((unsigned)v3));
    }
    __syncthreads();   // H

    // ---- I: window projection partials (lanes 0..59) ----
    #pragma unroll
    for (int bb = 0; bb < NB; ++bb) {
      const float* hb = &hx[bb][64 + kq*64 + wh*32];
      float a = 0.f;
      #pragma unroll
      for (int i4 = 0; i4 < 8; ++i4) {
        float4 h4 = *(const float4*)(hb + i4*4);
        a = fmaf(winreg[i4*4+0], h4.x, a);
        a = fmaf(winreg[i4*4+1], h4.y, a);
        a = fmaf(winreg[i4*4+2], h4.z, a);
        a = fmaf(winreg[i4*4+3], h4.w, a);
      }
      if (lane < 60) part[kq][bb][0][lane] = a;
    }
    __syncthreads();   // J

    // ---- K: finish p = exp(h@winW^T + winb); update kappa ----
    if (tid < 120) {
      int bb = tid / 30, j = tid % 30;
      float s = 0.f;
      #pragma unroll
      for (int q = 0; q < KQ; ++q) s += part[q][bb][0][j] + part[q][bb][0][30+j];
      float p = __expf(s + winb_r);
      p_lds[bb][j] = p;
      if (j >= 20) {
        float nk = kap_lds[bb][j-20] + p;
        kap_lds[bb][j-20] = nk;
        if (t == T_-1 && gblk == 0) out[OUT_KAP + (b0+bb)*K_ + (j-20)] = nk;
      }
    }
    __syncthreads();   // L

    // ---- M: fused phi + w-scatter (wave = batch; u = lane) ----
    if (kq < NB) {
      int bb = kq, u = lane;
      float s = 0.f;
      float uf = (float)u;
      #pragma unroll
      for (int k = 0; k < K_; ++k) {
        float d = kap_lds[bb][k] - uf;
        s += p_lds[bb][k] * __expf(-p_lds[bb][10+k]*d*d);
      }
      float phiv = s * scale_lds[bb];
      atomicAdd(&hx[bb][4 + ids_lds[bb][u]], phiv);   // ds_add_f32, in-wave order
      if (t == T_-1 && gblk == 0) out[OUT_PHI + (b0+bb)*65 + u] = phiv;
    }
    if (t == T_-1 && gblk == 0 && tid < NB) {         // u = 64 tail of phi output
      int b2 = tid;
      float s2 = 0.f;
      #pragma unroll
      for (int k = 0; k < K_; ++k) {
        float d = kap_lds[b2][k] - 64.f;
        s2 += p_lds[b2][k] * __expf(-p_lds[b2][10+k]*d*d);
      }
      out[OUT_PHI + (b0+b2)*65 + 64] = s2 * scale_lds[b2];
    }
    __syncthreads();   // N: scatter complete -> w readable

    // ---- O: rotated ws-store (one WG of the group per step) ----
    if (gblk == (t & 15) && tid < 240) {
      int bb = tid / 60, v = tid % 60;
      float wv = hx[bb][4+v];
      out[OUT_WS + ((long)(b0+bb)*T_ + t)*V_ + v] = wv;
      if (t == T_-1) out[OUT_W + (b0+bb)*V_ + v] = wv;
    }
    // no sync: O and next-A only read hx; first write is next-C (post-B sync)
  }
}

extern "C" void kernel_launch(void* const* d_in, const int* in_sizes, int n_in,
                              void* d_out, int out_size, void* d_ws, size_t ws_size,
                              hipStream_t stream) {
  const float* x         = (const float*)d_in[0];
  const float* onehots   = (const float*)d_in[1];
  const float* text_lens = (const float*)d_in[2];
  const float* w_old     = (const float*)d_in[3];
  const float* kappa_old = (const float*)d_in[4];
  const float* prev_h    = (const float*)d_in[5];
  const float* prev_c    = (const float*)d_in[6];
  const float* W_ih      = (const float*)d_in[7];
  const float* W_hh      = (const float*)d_in[8];
  const float* b_ih      = (const float*)d_in[9];
  const float* b_hh      = (const float*)d_in[10];
  const float* win_W     = (const float*)d_in[11];
  const float* win_b     = (const float*)d_in[12];
  unsigned long long* hpair = (unsigned long long*)d_ws;
  float* out = (float*)d_out;

  // zero the (h,tag) pair region (tags must start below 1; replay leaves stale tags)
  hipMemsetAsync(d_ws, 0, 2ull*B_*C_*sizeof(unsigned long long), stream);

  lstm_attn_persistent<<<NWG, NTH, 0, stream>>>(
      x, onehots, text_lens, w_old, kappa_old, prev_h, prev_c,
      W_ih, W_hh, b_ih, b_hh, win_W, win_b, hpair, out);
}